// Round 4
// baseline (1096.164 us; speedup 1.0000x reference)
//
#include <hip/hip_runtime.h>
#include <hip/hip_bf16.h>
#include <hip/hip_fp8.h>

typedef __attribute__((ext_vector_type(8))) short short8;
typedef __attribute__((ext_vector_type(4))) float f32x4;
typedef __attribute__((ext_vector_type(16))) float f32x16;

#define AS1 __attribute__((address_space(1)))
#define AS3 __attribute__((address_space(3)))

static constexpr int Mdim = 4096;
static constexpr int Kdim = 7168;
static constexpr int Ndim = 16384;
static constexpr float FP8_MAX = 448.0f;

// compiler-fence + raw barrier (no implicit vmcnt(0) drain)
#define BARRIER() do { asm volatile("" ::: "memory"); \
                       __builtin_amdgcn_s_barrier();  \
                       asm volatile("" ::: "memory"); } while (0)

#define MFMA32 __builtin_amdgcn_mfma_f32_32x32x16_bf16

// ---------------------------------------------------------------------------
// Kernel 1: activation quant  x[M,K] f32 -> xdq[M,K] bf16 (per 1x128 block)
// ---------------------------------------------------------------------------
__global__ __launch_bounds__(256) void quant_x_kernel(
    const float* __restrict__ x, __hip_bfloat16* __restrict__ xdq)
{
    constexpr int NBLK = Mdim * (Kdim / 128);
    const int lane = threadIdx.x & 63;
    const int wid  = (blockIdx.x * 256 + threadIdx.x) >> 6;
    const int nw   = (gridDim.x * 256) >> 6;

    for (int b = wid; b < NBLK; b += nw) {
        size_t base = (size_t)b * 128 + lane * 2;
        float2 v = *reinterpret_cast<const float2*>(x + base);
        float amax = fmaxf(fabsf(v.x), fabsf(v.y));
#pragma unroll
        for (int off = 32; off > 0; off >>= 1)
            amax = fmaxf(amax, __shfl_xor(amax, off));
        float s = amax * (1.0f / FP8_MAX);
        float q0 = 0.0f, q1 = 0.0f;
        if (s > 0.0f) {
            q0 = (float)__hip_fp8_e4m3(v.x / s) * s;
            q1 = (float)__hip_fp8_e4m3(v.y / s) * s;
        }
        __hip_bfloat162 o;
        o.x = __float2bfloat16(q0);
        o.y = __float2bfloat16(q1);
        *reinterpret_cast<__hip_bfloat162*>(xdq + base) = o;
    }
}

// ---------------------------------------------------------------------------
// Kernel 2: weight quant  w[N,K] f32 -> wdq[N,K] bf16
// ---------------------------------------------------------------------------
__global__ __launch_bounds__(256) void quant_w_kernel(
    const float* __restrict__ w, const float* __restrict__ ws,
    __hip_bfloat16* __restrict__ wdq)
{
    constexpr size_t NCHUNK = (size_t)Ndim * Kdim / 8;
    constexpr int CPR = Kdim / 8;
    constexpr int KB  = Kdim / 128;

    size_t idx    = (size_t)blockIdx.x * 256 + threadIdx.x;
    size_t stride = (size_t)gridDim.x * 256;

    for (size_t c = idx; c < NCHUNK; c += stride) {
        int n  = (int)(c / CPR);
        int kc = (int)(c - (size_t)n * CPR);
        int k  = kc * 8;
        float s = ws[(n >> 7) * KB + (k >> 7)];
        const float* src = w + (size_t)n * Kdim + k;
        float4 v0 = *reinterpret_cast<const float4*>(src);
        float4 v1 = *reinterpret_cast<const float4*>(src + 4);

        __hip_bfloat16 h[8];
        h[0] = __float2bfloat16((float)__hip_fp8_e4m3(v0.x) * s);
        h[1] = __float2bfloat16((float)__hip_fp8_e4m3(v0.y) * s);
        h[2] = __float2bfloat16((float)__hip_fp8_e4m3(v0.z) * s);
        h[3] = __float2bfloat16((float)__hip_fp8_e4m3(v0.w) * s);
        h[4] = __float2bfloat16((float)__hip_fp8_e4m3(v1.x) * s);
        h[5] = __float2bfloat16((float)__hip_fp8_e4m3(v1.y) * s);
        h[6] = __float2bfloat16((float)__hip_fp8_e4m3(v1.z) * s);
        h[7] = __float2bfloat16((float)__hip_fp8_e4m3(v1.w) * s);
        *reinterpret_cast<short8*>(wdq + (size_t)n * Kdim + k) =
            *reinterpret_cast<short8*>(h);
    }
}

// ---------------------------------------------------------------------------
// Kernel 3: 256x256 8-phase NT GEMM, 32x32x16 MFMA edition
//
// Same schedule/regions/swizzle/vmcnt as round 3 (verified):
//   LDS 128 KiB = 2 buf x { A0,A1,B0,B1 } regions of [128 rows][128 B];
//   swizzle phys_col = logical_col ^ ((row&7)<<4) on ds_read AND on the
//   global source of global_load_lds (linear LDS dest — rule #21);
//   stage stream j=4t+r (r 0:B0 1:B1 2:A0 3:A1), issue at phase j-6,
//   vmcnt(4) per tile boundary, drain to 0 for the last two tiles.
//
// Changes vs round 3:
//   - MFMA shape 16x16x32 -> 32x32x16: 8 MFMA/phase instead of 16, same
//     FLOP, same frag/acc register counts, +15% measured pipe rate.
//     A/B frag: row/col = lane&31, k = (lane>>5)*8 + e  (short8).
//     C/D: col = lane&31, row = (reg&3) + 8*(reg>>2) + 4*(lane>>5).
//   - stage addresses precomputed per-thread (one ptr add per call).
// Per-tile quadrants: P0: m0-1 x n0 | P1: m0-1 x n1 | P2: m2-3 x n0 |
//                     P3: m2-3 x n1   (each x 4 k-slices of 16)
// ---------------------------------------------------------------------------
constexpr int BM = 256, BN = 256, BK = 64;
constexpr int NT  = Kdim / BK;            // 112 K-tiles
constexpr int NBN = Ndim / BN;            // 64
constexpr int NWG = (Mdim / BM) * NBN;    // 1024 (%8 == 0)
constexpr int K2  = Kdim * 2;             // row stride in bytes

__global__ __launch_bounds__(512, 2) void gemm256_kernel(
    const __hip_bfloat16* __restrict__ Ag,
    const __hip_bfloat16* __restrict__ Bg,
    float* __restrict__ C)
{
    extern __shared__ char smem[];   // 131072 bytes

    const int tid  = threadIdx.x;
    const int w    = tid >> 6;
    const int lane = tid & 63;
    const int wr   = w >> 2;          // 0..1
    const int wc   = w & 3;           // 0..3
    const int l31  = lane & 31;
    const int hi16 = (lane >> 5) * 16;     // k-group byte offset

    // XCD-bijective block swizzle
    int bid = (int)blockIdx.x;
    int swz = (bid & 7) * (NWG >> 3) + (bid >> 3);
    const int bm = (swz / NBN) * BM;
    const int bn = (swz % NBN) * BN;

    // swizzled ds_read column offsets per k-slice (rows of every fragment
    // read satisfy row&7 == lane&7)
    const int sw = (lane & 7) << 4;
    int colks[4];
#pragma unroll
    for (int ks = 0; ks < 4; ++ks) colks[ks] = (ks * 32 + hi16) ^ sw;
    const int bRow = (wc & 1) * 64;   // wave's row base inside its B region

    // staging per-thread constants: phys 16B chunk -> swizzled global offset
    size_t offG[2];
    int    ldsW[2];
#pragma unroll
    for (int q = 0; q < 2; ++q) {
        int chp  = (w * 2 + q) * 64 + lane;            // 0..1023 (16B units)
        int row  = chp >> 3;                           // 0..127
        int colb = ((chp & 7) ^ (row & 7)) * 16;       // swizzled byte col
        offG[q]  = (size_t)row * K2 + colb;
        ldsW[q]  = (w * 2 + q) * 1024;                 // linear LDS dest
    }
    const char* Ab = (const char*)Ag + (size_t)bm * K2;
    const char* Bb = (const char*)Bg + (size_t)bn * K2;

    auto stage = [&](int j) {
        if (j >= 4 * NT) return;
        const int T    = j >> 2;
        const int r    = j & 3;          // 0:B0 1:B1 2:A0 3:A1
        const int isA  = r >> 1;
        const int half = r & 1;
        const int regByte = (T & 1) * 65536 + (isA ? 0 : 32768) + half * 16384;
        const char* g = (isA ? Ab : Bb) + (size_t)half * (128 * (size_t)K2)
                        + (size_t)T * 128;
#pragma unroll
        for (int q = 0; q < 2; ++q)
            __builtin_amdgcn_global_load_lds((const AS1 void*)(g + offG[q]),
                                             (AS3 void*)(smem + regByte + ldsW[q]),
                                             16, 0, 0);
    };

    // ---- prologue: tile0 (all 4 halves) + tile1 (B0,B1) ----
    for (int j = 0; j < 6; ++j) stage(j);
    asm volatile("s_waitcnt vmcnt(4)" ::: "memory");
    BARRIER();

    f32x16 acc[4][2] = {};

    for (int t = 0; t < NT; ++t) {
        const int buf = t & 1;
        const char* aB = smem + buf * 65536 + wr * 16384;
        const char* bB = smem + buf * 65536 + 32768 + (wc >> 1) * 16384;
        short8 a0[2][4], a1[2][4], b0[4], b1[4];

        // ---------------- P0 : m0-1 x n0 ----------------
#pragma unroll
        for (int m = 0; m < 2; ++m) {
            const char* p = aB + (m * 32 + l31) * 128;
#pragma unroll
            for (int ks = 0; ks < 4; ++ks)
                a0[m][ks] = *(const short8*)(p + colks[ks]);
        }
        {
            const char* p = bB + (bRow + l31) * 128;
#pragma unroll
            for (int ks = 0; ks < 4; ++ks)
                b0[ks] = *(const short8*)(p + colks[ks]);
        }
        stage(4 * t + 6);
        BARRIER();
        __builtin_amdgcn_s_setprio(1);
#pragma unroll
        for (int m = 0; m < 2; ++m)
#pragma unroll
            for (int ks = 0; ks < 4; ++ks)
                acc[m][0] = MFMA32(a0[m][ks], b0[ks], acc[m][0], 0, 0, 0);
        __builtin_amdgcn_s_setprio(0);
        BARRIER();

        // ---------------- P1 : m0-1 x n1 ----------------
        {
            const char* p = bB + (bRow + 32 + l31) * 128;
#pragma unroll
            for (int ks = 0; ks < 4; ++ks)
                b1[ks] = *(const short8*)(p + colks[ks]);
        }
        stage(4 * t + 7);
        BARRIER();
        __builtin_amdgcn_s_setprio(1);
#pragma unroll
        for (int m = 0; m < 2; ++m)
#pragma unroll
            for (int ks = 0; ks < 4; ++ks)
                acc[m][1] = MFMA32(a0[m][ks], b1[ks], acc[m][1], 0, 0, 0);
        __builtin_amdgcn_s_setprio(0);
        BARRIER();

        // ---------------- P2 : m2-3 x n0 ----------------
#pragma unroll
        for (int m = 0; m < 2; ++m) {
            const char* p = aB + ((m + 2) * 32 + l31) * 128;
#pragma unroll
            for (int ks = 0; ks < 4; ++ks)
                a1[m][ks] = *(const short8*)(p + colks[ks]);
        }
        stage(4 * t + 8);
        BARRIER();
        __builtin_amdgcn_s_setprio(1);
#pragma unroll
        for (int m = 0; m < 2; ++m)
#pragma unroll
            for (int ks = 0; ks < 4; ++ks)
                acc[m + 2][0] = MFMA32(a1[m][ks], b0[ks], acc[m + 2][0], 0, 0, 0);
        __builtin_amdgcn_s_setprio(0);
        BARRIER();

        // ---------------- P3 : m2-3 x n1 ----------------
        stage(4 * t + 9);
        BARRIER();
        __builtin_amdgcn_s_setprio(1);
#pragma unroll
        for (int m = 0; m < 2; ++m)
#pragma unroll
            for (int ks = 0; ks < 4; ++ks)
                acc[m + 2][1] = MFMA32(a1[m][ks], b1[ks], acc[m + 2][1], 0, 0, 0);
        __builtin_amdgcn_s_setprio(0);
        if (t < NT - 2) { asm volatile("s_waitcnt vmcnt(4)" ::: "memory"); }
        else            { asm volatile("s_waitcnt vmcnt(0)" ::: "memory"); }
        BARRIER();
    }

    // ---- epilogue: 32x32 C/D: col = lane&31, row = (reg&3)+8*(reg>>2)+4*(lane>>5)
    const int rsub = 4 * (lane >> 5);
#pragma unroll
    for (int m = 0; m < 4; ++m) {
#pragma unroll
        for (int n = 0; n < 2; ++n) {
            const f32x16 v   = acc[m][n];
            const int    col = bn + wc * 64 + n * 32 + l31;
            const int    rb  = bm + wr * 128 + m * 32 + rsub;
#pragma unroll
            for (int reg = 0; reg < 16; ++reg) {
                const int row = rb + (reg & 3) + 8 * (reg >> 2);
                C[(size_t)row * Ndim + col] = v[reg];
            }
        }
    }
}

// ---------------------------------------------------------------------------
extern "C" void kernel_launch(void* const* d_in, const int* in_sizes, int n_in,
                              void* d_out, int out_size, void* d_ws, size_t ws_size,
                              hipStream_t stream) {
    const float* x  = (const float*)d_in[0];
    const float* w  = (const float*)d_in[1];
    const float* ws = (const float*)d_in[2];

    __hip_bfloat16* xdq = (__hip_bfloat16*)d_ws;
    __hip_bfloat16* wdq = xdq + (size_t)Mdim * Kdim;

    quant_x_kernel<<<2048, 256, 0, stream>>>(x, xdq);
    quant_w_kernel<<<4096, 256, 0, stream>>>(w, ws, wdq);

    hipFuncSetAttribute((const void*)gemm256_kernel,
                        hipFuncAttributeMaxDynamicSharedMemorySize, 131072);
    gemm256_kernel<<<NWG, 512, 131072, stream>>>(xdq, wdq, (float*)d_out);
}

// Round 6
// 988.549 us; speedup vs baseline: 1.1089x; 1.1089x over previous
//
#include <hip/hip_runtime.h>
#include <hip/hip_bf16.h>
#include <hip/hip_fp8.h>

typedef __attribute__((ext_vector_type(8))) short short8;
typedef __attribute__((ext_vector_type(4))) float f32x4;

#define AS1 __attribute__((address_space(1)))
#define AS3 __attribute__((address_space(3)))

static constexpr int Mdim = 4096;
static constexpr int Kdim = 7168;
static constexpr int Ndim = 16384;
static constexpr float FP8_MAX = 448.0f;

// compiler-fence + raw barrier (no implicit vmcnt(0) drain)
#define BARRIER() do { asm volatile("" ::: "memory"); \
                       __builtin_amdgcn_s_barrier();  \
                       asm volatile("" ::: "memory"); } while (0)

// full LDS drain + scheduler pin (rule #18) before the MFMA cluster
#define LGKM0() do { asm volatile("s_waitcnt lgkmcnt(0)" ::: "memory"); \
                     __builtin_amdgcn_sched_barrier(0); } while (0)

#define MFMA_BF16 __builtin_amdgcn_mfma_f32_16x16x32_bf16

// ---------------------------------------------------------------------------
// Kernel 1: activation quant  x[M,K] f32 -> xdq[M,K] bf16 (per 1x128 block)
// ---------------------------------------------------------------------------
__global__ __launch_bounds__(256) void quant_x_kernel(
    const float* __restrict__ x, __hip_bfloat16* __restrict__ xdq)
{
    constexpr int NBLK = Mdim * (Kdim / 128);
    const int lane = threadIdx.x & 63;
    const int wid  = (blockIdx.x * 256 + threadIdx.x) >> 6;
    const int nw   = (gridDim.x * 256) >> 6;

    for (int b = wid; b < NBLK; b += nw) {
        size_t base = (size_t)b * 128 + lane * 2;
        float2 v = *reinterpret_cast<const float2*>(x + base);
        float amax = fmaxf(fabsf(v.x), fabsf(v.y));
#pragma unroll
        for (int off = 32; off > 0; off >>= 1)
            amax = fmaxf(amax, __shfl_xor(amax, off));
        float s = amax * (1.0f / FP8_MAX);
        float q0 = 0.0f, q1 = 0.0f;
        if (s > 0.0f) {
            q0 = (float)__hip_fp8_e4m3(v.x / s) * s;
            q1 = (float)__hip_fp8_e4m3(v.y / s) * s;
        }
        __hip_bfloat162 o;
        o.x = __float2bfloat16(q0);
        o.y = __float2bfloat16(q1);
        *reinterpret_cast<__hip_bfloat162*>(xdq + base) = o;
    }
}

// ---------------------------------------------------------------------------
// Kernel 2: weight quant  w[N,K] f32 -> wdq[N,K] bf16
// ---------------------------------------------------------------------------
__global__ __launch_bounds__(256) void quant_w_kernel(
    const float* __restrict__ w, const float* __restrict__ ws,
    __hip_bfloat16* __restrict__ wdq)
{
    constexpr size_t NCHUNK = (size_t)Ndim * Kdim / 8;
    constexpr int CPR = Kdim / 8;
    constexpr int KB  = Kdim / 128;

    size_t idx    = (size_t)blockIdx.x * 256 + threadIdx.x;
    size_t stride = (size_t)gridDim.x * 256;

    for (size_t c = idx; c < NCHUNK; c += stride) {
        int n  = (int)(c / CPR);
        int kc = (int)(c - (size_t)n * CPR);
        int k  = kc * 8;
        float s = ws[(n >> 7) * KB + (k >> 7)];
        const float* src = w + (size_t)n * Kdim + k;
        float4 v0 = *reinterpret_cast<const float4*>(src);
        float4 v1 = *reinterpret_cast<const float4*>(src + 4);

        __hip_bfloat16 h[8];
        h[0] = __float2bfloat16((float)__hip_fp8_e4m3(v0.x) * s);
        h[1] = __float2bfloat16((float)__hip_fp8_e4m3(v0.y) * s);
        h[2] = __float2bfloat16((float)__hip_fp8_e4m3(v0.z) * s);
        h[3] = __float2bfloat16((float)__hip_fp8_e4m3(v0.w) * s);
        h[4] = __float2bfloat16((float)__hip_fp8_e4m3(v1.x) * s);
        h[5] = __float2bfloat16((float)__hip_fp8_e4m3(v1.y) * s);
        h[6] = __float2bfloat16((float)__hip_fp8_e4m3(v1.z) * s);
        h[7] = __float2bfloat16((float)__hip_fp8_e4m3(v1.w) * s);
        *reinterpret_cast<short8*>(wdq + (size_t)n * Kdim + k) =
            *reinterpret_cast<short8*>(h);
    }
}

// ---------------------------------------------------------------------------
// Kernel 3: 256x256 8-phase NT GEMM, 16x16x32 MFMA (round-3 base, verified)
// with m201 phase ordering: ds_reads issued BEFORE the leading barrier,
// explicit lgkmcnt(0)+sched_barrier(0) after it, then the 16-MFMA cluster.
//
// Geometry/swizzle/staging identical to round 3 (0 bank conflicts):
//   LDS 128 KiB = 2 buf x { A0,A1,B0,B1 } regions of [128 rows][128 B];
//   swizzle phys_col = logical_col ^ ((row&7)<<4) on ds_read AND on the
//   global source of global_load_lds (linear LDS dest — rule #21);
//   stage stream j (j&3: 0:B0 1:B1 2:A0 3:A1 of tile j>>2, buffer (j>>2)&1),
//   one stage call per phase (issue at phase j-6).
//
// vmcnt: tile-boundary only (round-3 scheme). vmcnt(4) at P3 of tile t
// guarantees j <= 4t+7 complete, i.e. tile t+1 is FULLY LDS-resident before
// tile t+1's first pre-window — so every within-tile read is legal at any
// issue point. Overwrite safety: a region's reads are executed (lgkmcnt(0)
// in their phase) >= 2 barriers before that region's next stage write;
// A-region writes are always cross-buffer.
//
// Per-tile phases (reads pre-barrier):
//   P0: stage(4t+6); read a0(8),b0(4); BAR; LGKM0; Q0 = m0-3 x n0-1; BAR
//   P1: stage(4t+7); read b1(4);       BAR; LGKM0; Q1 = m0-3 x n2-3; BAR
//   P2: stage(4t+8); read a1(8);       BAR; LGKM0; Q2 = m4-7 x n0-1; BAR
//   P3: stage(4t+9);                   BAR;        Q3 = m4-7 x n2-3;
//       vmcnt(4 | 0); BAR
// ---------------------------------------------------------------------------
constexpr int BM = 256, BN = 256, BK = 64;
constexpr int NT  = Kdim / BK;            // 112 K-tiles
constexpr int NBN = Ndim / BN;            // 64
constexpr int NWG = (Mdim / BM) * NBN;    // 1024 (%8 == 0)
constexpr int K2  = Kdim * 2;             // row stride in bytes

__global__ __launch_bounds__(512, 2) void gemm256_kernel(
    const __hip_bfloat16* __restrict__ Ag,
    const __hip_bfloat16* __restrict__ Bg,
    float* __restrict__ C)
{
    extern __shared__ char smem[];   // 131072 bytes

    const int tid  = threadIdx.x;
    const int w    = tid >> 6;
    const int lane = tid & 63;
    const int wr   = w >> 2;          // 0..1
    const int wc   = w & 3;           // 0..3
    const int lr   = lane & 15;
    const int lk   = lane >> 4;

    // XCD-bijective block swizzle
    int bid = (int)blockIdx.x;
    int swz = (bid & 7) * (NWG >> 3) + (bid >> 3);
    const int bm = (swz / NBN) * BM;
    const int bn = (swz % NBN) * BN;

    // swizzled ds_read column offsets (row&7 == lr&7 for every fragment row)
    const int sw   = (lr & 7) << 4;
    const int col0 = (lk * 16) ^ sw;         // ks = 0
    const int col1 = (64 + lk * 16) ^ sw;    // ks = 1
    const int bRow = (wc & 1) * 64;          // wave's row base in its B region

    // staging: phys 16B chunk -> swizzled global offset, linear LDS dest
    size_t offG[2];
    int    ldsW[2];
#pragma unroll
    for (int q = 0; q < 2; ++q) {
        int chp  = (w * 2 + q) * 64 + lane;            // 0..1023 (16B units)
        int row  = chp >> 3;                           // 0..127
        int colb = ((chp & 7) ^ (row & 7)) * 16;       // swizzled byte col
        offG[q]  = (size_t)row * K2 + colb;
        ldsW[q]  = (w * 2 + q) * 1024;
    }
    const char* Ab = (const char*)Ag + (size_t)bm * K2;
    const char* Bb = (const char*)Bg + (size_t)bn * K2;

    auto stage = [&](int j) {
        if (j >= 4 * NT) return;
        const int T    = j >> 2;
        const int r    = j & 3;          // 0:B0 1:B1 2:A0 3:A1
        const int isA  = r >> 1;
        const int half = r & 1;
        const int regByte = (T & 1) * 65536 + (isA ? 0 : 32768) + half * 16384;
        const char* g = (isA ? Ab : Bb) + (size_t)half * (128 * (size_t)K2)
                        + (size_t)T * 128;
#pragma unroll
        for (int q = 0; q < 2; ++q)
            __builtin_amdgcn_global_load_lds((const AS1 void*)(g + offG[q]),
                                             (AS3 void*)(smem + regByte + ldsW[q]),
                                             16, 0, 0);
    };

    // ---- prologue: tile0 (all 4 halves) + tile1 (B0,B1) ----
    for (int j = 0; j < 6; ++j) stage(j);
    asm volatile("s_waitcnt vmcnt(4)" ::: "memory");   // j<=3: tile0 resident
    BARRIER();

    f32x4 acc[8][4] = {};

    for (int t = 0; t < NT; ++t) {
        const int buf = t & 1;
        const char* aB = smem + buf * 65536 + wr * 16384;
        const char* bB = smem + buf * 65536 + 32768 + (wc >> 1) * 16384;
        short8 a0[4][2], a1[4][2], b0[2][2], b1[2][2];

        // ---------------- P0 : pre{stage, read a0,b0} | Q0 = m0-3 x n0-1 ----
        stage(4 * t + 6);
#pragma unroll
        for (int m = 0; m < 4; ++m) {
            const char* p = aB + (m * 16 + lr) * 128;
            a0[m][0] = *(const short8*)(p + col0);
            a0[m][1] = *(const short8*)(p + col1);
        }
#pragma unroll
        for (int n = 0; n < 2; ++n) {
            const char* p = bB + (bRow + n * 16 + lr) * 128;
            b0[n][0] = *(const short8*)(p + col0);
            b0[n][1] = *(const short8*)(p + col1);
        }
        BARRIER();
        LGKM0();
        __builtin_amdgcn_s_setprio(1);
#pragma unroll
        for (int m = 0; m < 4; ++m)
#pragma unroll
            for (int n = 0; n < 2; ++n) {
                acc[m][n] = MFMA_BF16(a0[m][0], b0[n][0], acc[m][n], 0, 0, 0);
                acc[m][n] = MFMA_BF16(a0[m][1], b0[n][1], acc[m][n], 0, 0, 0);
            }
        __builtin_amdgcn_s_setprio(0);
        BARRIER();

        // ---------------- P1 : pre{stage, read b1} | Q1 = m0-3 x n2-3 -------
        stage(4 * t + 7);
#pragma unroll
        for (int n = 0; n < 2; ++n) {
            const char* p = bB + (bRow + (n + 2) * 16 + lr) * 128;
            b1[n][0] = *(const short8*)(p + col0);
            b1[n][1] = *(const short8*)(p + col1);
        }
        BARRIER();
        LGKM0();
        __builtin_amdgcn_s_setprio(1);
#pragma unroll
        for (int m = 0; m < 4; ++m)
#pragma unroll
            for (int n = 0; n < 2; ++n) {
                acc[m][n + 2] = MFMA_BF16(a0[m][0], b1[n][0], acc[m][n + 2], 0, 0, 0);
                acc[m][n + 2] = MFMA_BF16(a0[m][1], b1[n][1], acc[m][n + 2], 0, 0, 0);
            }
        __builtin_amdgcn_s_setprio(0);
        BARRIER();

        // ---------------- P2 : pre{stage, read a1} | Q2 = m4-7 x n0-1 -------
        stage(4 * t + 8);
#pragma unroll
        for (int m = 0; m < 4; ++m) {
            const char* p = aB + ((m + 4) * 16 + lr) * 128;
            a1[m][0] = *(const short8*)(p + col0);
            a1[m][1] = *(const short8*)(p + col1);
        }
        BARRIER();
        LGKM0();
        __builtin_amdgcn_s_setprio(1);
#pragma unroll
        for (int m = 0; m < 4; ++m)
#pragma unroll
            for (int n = 0; n < 2; ++n) {
                acc[m + 4][n] = MFMA_BF16(a1[m][0], b0[n][0], acc[m + 4][n], 0, 0, 0);
                acc[m + 4][n] = MFMA_BF16(a1[m][1], b0[n][1], acc[m + 4][n], 0, 0, 0);
            }
        __builtin_amdgcn_s_setprio(0);
        BARRIER();

        // ---------------- P3 : pre{stage} | Q3 = m4-7 x n2-3 | vmcnt --------
        stage(4 * t + 9);
        BARRIER();
        __builtin_amdgcn_s_setprio(1);
#pragma unroll
        for (int m = 0; m < 4; ++m)
#pragma unroll
            for (int n = 0; n < 2; ++n) {
                acc[m + 4][n + 2] = MFMA_BF16(a1[m][0], b1[n][0], acc[m + 4][n + 2], 0, 0, 0);
                acc[m + 4][n + 2] = MFMA_BF16(a1[m][1], b1[n][1], acc[m + 4][n + 2], 0, 0, 0);
            }
        __builtin_amdgcn_s_setprio(0);
        if (t < NT - 2) { asm volatile("s_waitcnt vmcnt(4)" ::: "memory"); }
        else            { asm volatile("s_waitcnt vmcnt(0)" ::: "memory"); }
        BARRIER();
    }

    // ---- epilogue: C/D layout col = lr, row = lk*4 + j ----
#pragma unroll
    for (int m = 0; m < 8; ++m) {
#pragma unroll
        for (int n = 0; n < 4; ++n) {
            const int row0 = bm + wr * 128 + m * 16 + lk * 4;
            const int col  = bn + wc * 64 + n * 16 + lr;
#pragma unroll
            for (int j = 0; j < 4; ++j)
                C[(size_t)(row0 + j) * Ndim + col] = acc[m][n][j];
        }
    }
}

// ---------------------------------------------------------------------------
extern "C" void kernel_launch(void* const* d_in, const int* in_sizes, int n_in,
                              void* d_out, int out_size, void* d_ws, size_t ws_size,
                              hipStream_t stream) {
    const float* x  = (const float*)d_in[0];
    const float* w  = (const float*)d_in[1];
    const float* ws = (const float*)d_in[2];

    __hip_bfloat16* xdq = (__hip_bfloat16*)d_ws;
    __hip_bfloat16* wdq = xdq + (size_t)Mdim * Kdim;

    quant_x_kernel<<<2048, 256, 0, stream>>>(x, xdq);
    quant_w_kernel<<<4096, 256, 0, stream>>>(w, ws, wdq);

    hipFuncSetAttribute((const void*)gemm256_kernel,
                        hipFuncAttributeMaxDynamicSharedMemorySize, 131072);
    gemm256_kernel<<<NWG, 512, 131072, stream>>>(xdq, wdq, (float*)d_out);
}

// Round 7
// 956.177 us; speedup vs baseline: 1.1464x; 1.0339x over previous
//
#include <hip/hip_runtime.h>
#include <hip/hip_bf16.h>
#include <hip/hip_fp8.h>

typedef __attribute__((ext_vector_type(8))) short short8;
typedef __attribute__((ext_vector_type(4))) float f32x4;

#define AS1 __attribute__((address_space(1)))
#define AS3 __attribute__((address_space(3)))

static constexpr int Mdim = 4096;
static constexpr int Kdim = 7168;
static constexpr int Ndim = 16384;
static constexpr float FP8_MAX = 448.0f;

// compiler-fence + raw barrier (no implicit vmcnt(0) drain)
#define BARRIER() do { asm volatile("" ::: "memory"); \
                       __builtin_amdgcn_s_barrier();  \
                       asm volatile("" ::: "memory"); } while (0)

#define MFMA_BF16 __builtin_amdgcn_mfma_f32_16x16x32_bf16

// ---------------------------------------------------------------------------
// Kernel 1: activation quant  x[M,K] f32 -> xdq[M,K] bf16 (per 1x128 block)
// ---------------------------------------------------------------------------
__global__ __launch_bounds__(256) void quant_x_kernel(
    const float* __restrict__ x, __hip_bfloat16* __restrict__ xdq)
{
    constexpr int NBLK = Mdim * (Kdim / 128);
    const int lane = threadIdx.x & 63;
    const int wid  = (blockIdx.x * 256 + threadIdx.x) >> 6;
    const int nw   = (gridDim.x * 256) >> 6;

    for (int b = wid; b < NBLK; b += nw) {
        size_t base = (size_t)b * 128 + lane * 2;
        float2 v = *reinterpret_cast<const float2*>(x + base);
        float amax = fmaxf(fabsf(v.x), fabsf(v.y));
#pragma unroll
        for (int off = 32; off > 0; off >>= 1)
            amax = fmaxf(amax, __shfl_xor(amax, off));
        float s = amax * (1.0f / FP8_MAX);
        float q0 = 0.0f, q1 = 0.0f;
        if (s > 0.0f) {
            q0 = (float)__hip_fp8_e4m3(v.x / s) * s;
            q1 = (float)__hip_fp8_e4m3(v.y / s) * s;
        }
        __hip_bfloat162 o;
        o.x = __float2bfloat16(q0);
        o.y = __float2bfloat16(q1);
        *reinterpret_cast<__hip_bfloat162*>(xdq + base) = o;
    }
}

// ---------------------------------------------------------------------------
// Kernel 2: weight quant  w[N,K] f32 -> wdq[N,K] bf16
// ---------------------------------------------------------------------------
__global__ __launch_bounds__(256) void quant_w_kernel(
    const float* __restrict__ w, const float* __restrict__ ws,
    __hip_bfloat16* __restrict__ wdq)
{
    constexpr size_t NCHUNK = (size_t)Ndim * Kdim / 8;
    constexpr int CPR = Kdim / 8;
    constexpr int KB  = Kdim / 128;

    size_t idx    = (size_t)blockIdx.x * 256 + threadIdx.x;
    size_t stride = (size_t)gridDim.x * 256;

    for (size_t c = idx; c < NCHUNK; c += stride) {
        int n  = (int)(c / CPR);
        int kc = (int)(c - (size_t)n * CPR);
        int k  = kc * 8;
        float s = ws[(n >> 7) * KB + (k >> 7)];
        const float* src = w + (size_t)n * Kdim + k;
        float4 v0 = *reinterpret_cast<const float4*>(src);
        float4 v1 = *reinterpret_cast<const float4*>(src + 4);

        __hip_bfloat16 h[8];
        h[0] = __float2bfloat16((float)__hip_fp8_e4m3(v0.x) * s);
        h[1] = __float2bfloat16((float)__hip_fp8_e4m3(v0.y) * s);
        h[2] = __float2bfloat16((float)__hip_fp8_e4m3(v0.z) * s);
        h[3] = __float2bfloat16((float)__hip_fp8_e4m3(v0.w) * s);
        h[4] = __float2bfloat16((float)__hip_fp8_e4m3(v1.x) * s);
        h[5] = __float2bfloat16((float)__hip_fp8_e4m3(v1.y) * s);
        h[6] = __float2bfloat16((float)__hip_fp8_e4m3(v1.z) * s);
        h[7] = __float2bfloat16((float)__hip_fp8_e4m3(v1.w) * s);
        *reinterpret_cast<short8*>(wdq + (size_t)n * Kdim + k) =
            *reinterpret_cast<short8*>(h);
    }
}

// ---------------------------------------------------------------------------
// Kernel 3: 256x256 NT GEMM, 16x16x32 MFMA, TWO barriers per K-tile
//
// Geometry/swizzle/staging identical to rounds 3/6 (verified, 0 conflicts):
//   LDS 128 KiB = 2 buf x { A0,A1,B0,B1 } regions of [128 rows][128 B];
//   swizzle phys_col = logical_col ^ ((row&7)<<4) on ds_read AND on the
//   global source of global_load_lds (linear LDS dest — rule #21);
//   stage stream j (j&3: 0:B0 1:B1 2:A0 3:A1 of tile j>>2, buffer (j>>2)&1).
//
// NEW: only 2 barriers per K-tile. Windows W1={Q0,Q1}, W2={Q2,Q3}.
// Safety proof (region-disjointness, all waves within one window between
// consecutive barriers):
//   W1 issues stage j=4t+6 (A0@buf^1), j=4t+7 (A1@buf^1);
//   W1 reads a0(A0@buf), b0(B0@buf), b1(B1@buf)       -> disjoint from writes.
//   W2 issues stage j=4t+8 (B0@buf, tile t+2), j=4t+9 (B1@buf, t+2);
//   W2 reads a1(A1@buf)                                -> disjoint.
//   Cross-window: B0/B1@buf overwrites (issued W2) vs tile-t b0/b1 reads
//   (issued W1): each wave's Q0/Q1 MFMAs consume b0/b1, so the compiler's
//   lgkm waits retire those ds_reads before the wave reaches the W1->W2
//   barrier; overwrites are issued only after ALL waves pass it.
//   A@buf^1 writes (issued W1) are read only in tile t+1 after the
//   tile-boundary vmcnt+barrier.
// Residency: vmcnt(4) at each tile boundary -> j<=4t+7 landed -> tile t+1
// fully LDS-resident before its first read (2 loads per stage call).
// Last two tiles drain vmcnt(0). No explicit lgkmcnt: the ds_reads are
// compiler-emitted, so hipcc inserts fine-grained lgkm waits itself.
// ---------------------------------------------------------------------------
constexpr int BM = 256, BN = 256, BK = 64;
constexpr int NT  = Kdim / BK;            // 112 K-tiles
constexpr int NBN = Ndim / BN;            // 64
constexpr int NWG = (Mdim / BM) * NBN;    // 1024 (%8 == 0)
constexpr int K2  = Kdim * 2;             // row stride in bytes

__global__ __launch_bounds__(512, 2) void gemm256_kernel(
    const __hip_bfloat16* __restrict__ Ag,
    const __hip_bfloat16* __restrict__ Bg,
    float* __restrict__ C)
{
    extern __shared__ char smem[];   // 131072 bytes

    const int tid  = threadIdx.x;
    const int w    = tid >> 6;
    const int lane = tid & 63;
    const int wr   = w >> 2;          // 0..1
    const int wc   = w & 3;           // 0..3
    const int lr   = lane & 15;
    const int lk   = lane >> 4;

    // XCD-bijective block swizzle
    int bid = (int)blockIdx.x;
    int swz = (bid & 7) * (NWG >> 3) + (bid >> 3);
    const int bm = (swz / NBN) * BM;
    const int bn = (swz % NBN) * BN;

    // swizzled ds_read column offsets (row&7 == lr&7 for every fragment row)
    const int sw   = (lr & 7) << 4;
    const int col0 = (lk * 16) ^ sw;         // ks = 0
    const int col1 = (64 + lk * 16) ^ sw;    // ks = 1
    const int bRow = (wc & 1) * 64;          // wave's row base in its B region

    // staging: phys 16B chunk -> swizzled global offset, linear LDS dest
    size_t offG[2];
    int    ldsW[2];
#pragma unroll
    for (int q = 0; q < 2; ++q) {
        int chp  = (w * 2 + q) * 64 + lane;            // 0..1023 (16B units)
        int row  = chp >> 3;                           // 0..127
        int colb = ((chp & 7) ^ (row & 7)) * 16;       // swizzled byte col
        offG[q]  = (size_t)row * K2 + colb;
        ldsW[q]  = (w * 2 + q) * 1024;
    }
    const char* Ab = (const char*)Ag + (size_t)bm * K2;
    const char* Bb = (const char*)Bg + (size_t)bn * K2;

    auto stage = [&](int j) {
        if (j >= 4 * NT) return;
        const int T    = j >> 2;
        const int r    = j & 3;          // 0:B0 1:B1 2:A0 3:A1
        const int isA  = r >> 1;
        const int half = r & 1;
        const int regByte = (T & 1) * 65536 + (isA ? 0 : 32768) + half * 16384;
        const char* g = (isA ? Ab : Bb) + (size_t)half * (128 * (size_t)K2)
                        + (size_t)T * 128;
#pragma unroll
        for (int q = 0; q < 2; ++q)
            __builtin_amdgcn_global_load_lds((const AS1 void*)(g + offG[q]),
                                             (AS3 void*)(smem + regByte + ldsW[q]),
                                             16, 0, 0);
    };

    // ---- prologue: tile0 (all 4 halves) + tile1 (B0,B1) ----
    for (int j = 0; j < 6; ++j) stage(j);
    asm volatile("s_waitcnt vmcnt(4)" ::: "memory");   // j<=3: tile0 resident
    BARRIER();

    f32x4 acc[8][4] = {};

    for (int t = 0; t < NT; ++t) {
        const int buf = t & 1;
        const char* aB = smem + buf * 65536 + wr * 16384;
        const char* bB = smem + buf * 65536 + 32768 + (wc >> 1) * 16384;
        short8 a0[4][2], a1[4][2], b0[2][2], b1[2][2];

        // ================= W1 : Q0 + Q1 =================
        stage(4 * t + 6);
#pragma unroll
        for (int m = 0; m < 4; ++m) {
            const char* p = aB + (m * 16 + lr) * 128;
            a0[m][0] = *(const short8*)(p + col0);
            a0[m][1] = *(const short8*)(p + col1);
        }
#pragma unroll
        for (int n = 0; n < 2; ++n) {
            const char* p = bB + (bRow + n * 16 + lr) * 128;
            b0[n][0] = *(const short8*)(p + col0);
            b0[n][1] = *(const short8*)(p + col1);
        }
        __builtin_amdgcn_s_setprio(1);
#pragma unroll
        for (int m = 0; m < 4; ++m)
#pragma unroll
            for (int n = 0; n < 2; ++n) {
                acc[m][n] = MFMA_BF16(a0[m][0], b0[n][0], acc[m][n], 0, 0, 0);
                acc[m][n] = MFMA_BF16(a0[m][1], b0[n][1], acc[m][n], 0, 0, 0);
            }
        __builtin_amdgcn_s_setprio(0);

        stage(4 * t + 7);
#pragma unroll
        for (int n = 0; n < 2; ++n) {
            const char* p = bB + (bRow + (n + 2) * 16 + lr) * 128;
            b1[n][0] = *(const short8*)(p + col0);
            b1[n][1] = *(const short8*)(p + col1);
        }
        __builtin_amdgcn_s_setprio(1);
#pragma unroll
        for (int m = 0; m < 4; ++m)
#pragma unroll
            for (int n = 0; n < 2; ++n) {
                acc[m][n + 2] = MFMA_BF16(a0[m][0], b1[n][0], acc[m][n + 2], 0, 0, 0);
                acc[m][n + 2] = MFMA_BF16(a0[m][1], b1[n][1], acc[m][n + 2], 0, 0, 0);
            }
        __builtin_amdgcn_s_setprio(0);
        BARRIER();   // W1 -> W2 (b0/b1 reads retired; B-overwrites may follow)

        // ================= W2 : Q2 + Q3 =================
        stage(4 * t + 8);
#pragma unroll
        for (int m = 0; m < 4; ++m) {
            const char* p = aB + ((m + 4) * 16 + lr) * 128;
            a1[m][0] = *(const short8*)(p + col0);
            a1[m][1] = *(const short8*)(p + col1);
        }
        __builtin_amdgcn_s_setprio(1);
#pragma unroll
        for (int m = 0; m < 4; ++m)
#pragma unroll
            for (int n = 0; n < 2; ++n) {
                acc[m + 4][n] = MFMA_BF16(a1[m][0], b0[n][0], acc[m + 4][n], 0, 0, 0);
                acc[m + 4][n] = MFMA_BF16(a1[m][1], b0[n][1], acc[m + 4][n], 0, 0, 0);
            }
        __builtin_amdgcn_s_setprio(0);

        stage(4 * t + 9);
        __builtin_amdgcn_s_setprio(1);
#pragma unroll
        for (int m = 0; m < 4; ++m)
#pragma unroll
            for (int n = 0; n < 2; ++n) {
                acc[m + 4][n + 2] = MFMA_BF16(a1[m][0], b1[n][0], acc[m + 4][n + 2], 0, 0, 0);
                acc[m + 4][n + 2] = MFMA_BF16(a1[m][1], b1[n][1], acc[m + 4][n + 2], 0, 0, 0);
            }
        __builtin_amdgcn_s_setprio(0);
        if (t < NT - 2) { asm volatile("s_waitcnt vmcnt(4)" ::: "memory"); }
        else            { asm volatile("s_waitcnt vmcnt(0)" ::: "memory"); }
        BARRIER();   // tile boundary: tile t+1 fully resident
    }

    // ---- epilogue: C/D layout col = lr, row = lk*4 + j ----
#pragma unroll
    for (int m = 0; m < 8; ++m) {
#pragma unroll
        for (int n = 0; n < 4; ++n) {
            const int row0 = bm + wr * 128 + m * 16 + lk * 4;
            const int col  = bn + wc * 64 + n * 16 + lr;
#pragma unroll
            for (int j = 0; j < 4; ++j)
                C[(size_t)(row0 + j) * Ndim + col] = acc[m][n][j];
        }
    }
}

// ---------------------------------------------------------------------------
extern "C" void kernel_launch(void* const* d_in, const int* in_sizes, int n_in,
                              void* d_out, int out_size, void* d_ws, size_t ws_size,
                              hipStream_t stream) {
    const float* x  = (const float*)d_in[0];
    const float* w  = (const float*)d_in[1];
    const float* ws = (const float*)d_in[2];

    __hip_bfloat16* xdq = (__hip_bfloat16*)d_ws;
    __hip_bfloat16* wdq = xdq + (size_t)Mdim * Kdim;

    quant_x_kernel<<<2048, 256, 0, stream>>>(x, xdq);
    quant_w_kernel<<<4096, 256, 0, stream>>>(w, ws, wdq);

    hipFuncSetAttribute((const void*)gemm256_kernel,
                        hipFuncAttributeMaxDynamicSharedMemorySize, 131072);
    gemm256_kernel<<<NWG, 512, 131072, stream>>>(xdq, wdq, (float*)d_out);
}